// Round 3
// baseline (453.331 us; speedup 1.0000x reference)
//
#include <hip/hip_runtime.h>
#include <math.h>

// SSIM loss: bilinear-resize input (384->512, align_corners) then SSIM vs target
// over 11x11 Gaussian windows (VALID), mean over (32,3,502,502), loss = clip(1-mean,0,1).
// R3: 4-channel trick (P=(a+b)^2, M=(a-b)^2), float2-packed h, 37.4KB LDS (4 blocks/CU),
//     f32 tables, vectorized target staging, register-resident gaussian.

constexpr int KS   = 11;
constexpr int TILE = 32;
constexpr int REG  = TILE + KS - 1;   // 42
constexpr int HI = 384, WI = 384;
constexpr int HO = 512, WO = 512;
constexpr int OUTD = HO - KS + 1;     // 502
constexpr int NPLANE = 96;            // 32*3
constexpr float C1 = 1.0e-4f;         // (0.01*1)^2
constexpr float C2 = 9.0e-4f;         // (0.03*1)^2

__global__ __launch_bounds__(256, 4)
void ssim_fused(const float* __restrict__ input, const float* __restrict__ target,
                double* __restrict__ accum)
{
    __shared__ float g[KS];
    __shared__ __align__(16) float  s1[REG][REG + 2];   // resized img1 region (pitch 44)
    __shared__ __align__(16) float  s2[REG][REG + 2];   // target region
    __shared__ __align__(16) float2 hA[REG][TILE];      // (conv_x a, conv_x b)
    __shared__ __align__(16) float2 hB[REG][TILE];      // (conv_x (a+b)^2, conv_x (a-b)^2)
    __shared__ int   yo0[REG], yo1[REG];
    __shared__ float ywt[REG];
    __shared__ int   xo0[REG], xo1[REG];
    __shared__ float xwt[REG];
    __shared__ float wave_sums[4];

    const int tid = threadIdx.x;
    const int bc  = blockIdx.z;
    const int oy0 = blockIdx.y * TILE;
    const int ox0 = blockIdx.x * TILE;

    // Gaussian weights
    if (tid == 0) {
        float tmp[KS]; float s = 0.f;
        #pragma unroll
        for (int i = 0; i < KS; ++i) {
            float d = (float)(i - KS / 2);
            tmp[i] = __expf(-d * d / (2.f * 1.5f * 1.5f));
            s += tmp[i];
        }
        #pragma unroll
        for (int i = 0; i < KS; ++i) g[i] = tmp[i] / s;
    }
    // per-axis bilinear tables (align_corners=True), f32 exact-enough:
    // pos = r*383/511; r*383 < 2^24 exact, result err ~1.5e-5 << 1/511 gap to integers.
    if (tid < REG) {
        int r = oy0 + tid; if (r > HO - 1) r = HO - 1;
        float p = (float)(r * (HI - 1)) / (float)(HO - 1);
        int i0 = (int)p;
        int i1 = i0 + 1; if (i1 > HI - 1) i1 = HI - 1;
        yo0[tid] = i0 * WI; yo1[tid] = i1 * WI; ywt[tid] = p - (float)i0;
    }
    if (tid >= 64 && tid < 64 + REG) {
        int t = tid - 64;
        int c = ox0 + t; if (c > WO - 1) c = WO - 1;
        float p = (float)(c * (WI - 1)) / (float)(WO - 1);
        int i0 = (int)p;
        int i1 = i0 + 1; if (i1 > WI - 1) i1 = WI - 1;
        xo0[t] = i0; xo1[t] = i1; xwt[t] = p - (float)i0;
    }
    __syncthreads();   // tables ready

    const float* ip = input  + (size_t)bc * HI * WI;
    const float* tp = target + (size_t)bc * HO * WO;

    // stage img1 (bilinear on the fly), scalar gathers
    for (int idx = tid; idx < REG * REG; idx += 256) {
        int ry = idx / REG, rx = idx - ry * REG;
        float wy = ywt[ry], wx = xwt[rx];
        int o0 = yo0[ry], o1 = yo1[ry], x0 = xo0[rx], x1 = xo1[rx];
        float v00 = ip[o0 + x0], v01 = ip[o0 + x1];
        float v10 = ip[o1 + x0], v11 = ip[o1 + x1];
        float top = v00 + wx * (v01 - v00);
        float bot = v10 + wx * (v11 - v10);
        s1[ry][rx] = top + wy * (bot - top);
    }
    // stage target region, vectorized float4 rows. Clamped loads near the plane
    // edge produce wrong values only in columns/rows that feed masked outputs.
    for (int it = tid; it < REG * 11; it += 256) {
        int ry = it / 11, k = it - ry * 11;
        int gy = oy0 + ry; if (gy > HO - 1) gy = HO - 1;
        int c4 = ox0 + k * 4; if (c4 > WO - 4) c4 = WO - 4;
        float4 v = *(const float4*)&tp[gy * WO + c4];
        *(float4*)&s2[ry][k * 4] = v;
    }
    __syncthreads();   // s1/s2 ready

    float grf[KS];
    #pragma unroll
    for (int j = 0; j < KS; ++j) grf[j] = g[j];   // broadcast reads, then register-resident

    // horizontal pass: 42 rows x 8 groups of 4 outputs = 336 items
    for (int item = tid; item < REG * (TILE / 4); item += 256) {
        int ry = item >> 3;
        int x0 = (item & 7) * 4;
        float4 a0 = *(const float4*)&s1[ry][x0];
        float4 a1 = *(const float4*)&s1[ry][x0 + 4];
        float4 a2 = *(const float4*)&s1[ry][x0 + 8];
        float4 a3 = *(const float4*)&s1[ry][x0 + 12];
        float4 b0 = *(const float4*)&s2[ry][x0];
        float4 b1 = *(const float4*)&s2[ry][x0 + 4];
        float4 b2 = *(const float4*)&s2[ry][x0 + 8];
        float4 b3 = *(const float4*)&s2[ry][x0 + 12];
        float av[16] = {a0.x,a0.y,a0.z,a0.w, a1.x,a1.y,a1.z,a1.w,
                        a2.x,a2.y,a2.z,a2.w, a3.x,a3.y,a3.z,a3.w};
        float bv[16] = {b0.x,b0.y,b0.z,b0.w, b1.x,b1.y,b1.z,b1.w,
                        b2.x,b2.y,b2.z,b2.w, b3.x,b3.y,b3.z,b3.w};
        float sq[16], dq[16];
        #pragma unroll
        for (int e = 0; e < 16; ++e) {
            float s = av[e] + bv[e];
            float d = av[e] - bv[e];
            sq[e] = s * s;
            dq[e] = d * d;
        }
        float m1[4] = {0,0,0,0}, m2[4] = {0,0,0,0};
        float P[4]  = {0,0,0,0}, M[4]  = {0,0,0,0};
        #pragma unroll
        for (int k = 0; k < 4; ++k) {
            #pragma unroll
            for (int j = 0; j < KS; ++j) {
                float w = grf[j];
                m1[k] = fmaf(w, av[k + j], m1[k]);
                m2[k] = fmaf(w, bv[k + j], m2[k]);
                P[k]  = fmaf(w, sq[k + j], P[k]);
                M[k]  = fmaf(w, dq[k + j], M[k]);
            }
        }
        float4 wa0 = make_float4(m1[0], m2[0], m1[1], m2[1]);
        float4 wa1 = make_float4(m1[2], m2[2], m1[3], m2[3]);
        float4 wb0 = make_float4(P[0],  M[0],  P[1],  M[1]);
        float4 wb1 = make_float4(P[2],  M[2],  P[3],  M[3]);
        *(float4*)&hA[ry][x0]     = wa0;
        *(float4*)&hA[ry][x0 + 2] = wa1;
        *(float4*)&hB[ry][x0]     = wb0;
        *(float4*)&hB[ry][x0 + 2] = wb1;
    }
    __syncthreads();   // h ready

    // vertical pass + SSIM: each thread 4 consecutive y at one x
    float lsum = 0.f;
    {
        int lx  = tid & 31;
        int ly0 = (tid >> 5) * 4;
        int oy  = oy0 + ly0, ox = ox0 + lx;

        float mu1[4] = {0,0,0,0}, mu2[4] = {0,0,0,0};
        {
            float2 w[14];
            #pragma unroll
            for (int r = 0; r < 14; ++r) w[r] = hA[ly0 + r][lx];
            #pragma unroll
            for (int k = 0; k < 4; ++k) {
                #pragma unroll
                for (int j = 0; j < KS; ++j) {
                    mu1[k] = fmaf(grf[j], w[k + j].x, mu1[k]);
                    mu2[k] = fmaf(grf[j], w[k + j].y, mu2[k]);
                }
            }
        }
        float vP[4] = {0,0,0,0}, vM[4] = {0,0,0,0};
        {
            float2 w[14];
            #pragma unroll
            for (int r = 0; r < 14; ++r) w[r] = hB[ly0 + r][lx];
            #pragma unroll
            for (int k = 0; k < 4; ++k) {
                #pragma unroll
                for (int j = 0; j < KS; ++j) {
                    vP[k] = fmaf(grf[j], w[k + j].x, vP[k]);
                    vM[k] = fmaf(grf[j], w[k + j].y, vM[k]);
                }
            }
        }
        #pragma unroll
        for (int k = 0; k < 4; ++k) {
            if (oy + k < OUTD && ox < OUTD) {
                float a = mu1[k], b = mu2[k];
                float aa = a * a, bb = b * b, ab = a * b;
                float s12  = 0.25f * (vP[k] - vM[k]) - ab;   // sigma12
                float ssum = 0.5f  * (vP[k] + vM[k]) - aa - bb; // sigma1+sigma2
                float v1 = 2.f * s12 + C2;
                float v2 = ssum + C2;
                float num = (2.f * ab + C1) * v1;
                float den = (aa + bb + C1) * v2;
                lsum += __fdividef(num, den);
            }
        }
    }

    // block reduction: wave64 shuffle (f32) + LDS across 4 waves, one f64 atomic
    #pragma unroll
    for (int off = 32; off > 0; off >>= 1) lsum += __shfl_down(lsum, off);
    int wave = tid >> 6, lane = tid & 63;
    if (lane == 0) wave_sums[wave] = lsum;
    __syncthreads();
    if (tid == 0) {
        float s = wave_sums[0] + wave_sums[1] + wave_sums[2] + wave_sums[3];
        atomicAdd(accum, (double)s);
    }
}

__global__ void ssim_finalize(const double* __restrict__ accum, float* __restrict__ out)
{
    if (threadIdx.x == 0 && blockIdx.x == 0) {
        double mean = accum[0] / ((double)NPLANE * OUTD * OUTD);
        double l = 1.0 - mean;
        if (l < 0.0) l = 0.0;
        if (l > 1.0) l = 1.0;
        out[0] = (float)l;
    }
}

extern "C" void kernel_launch(void* const* d_in, const int* in_sizes, int n_in,
                              void* d_out, int out_size, void* d_ws, size_t ws_size,
                              hipStream_t stream)
{
    const float* input  = (const float*)d_in[0];   // [32,3,384,384]
    const float* target = (const float*)d_in[1];   // [32,3,512,512]
    float* out = (float*)d_out;
    double* accum = (double*)d_ws;

    hipMemsetAsync(accum, 0, sizeof(double), stream);

    dim3 grid((OUTD + TILE - 1) / TILE, (OUTD + TILE - 1) / TILE, NPLANE);
    ssim_fused<<<grid, dim3(256), 0, stream>>>(input, target, accum);
    ssim_finalize<<<1, 64, 0, stream>>>(accum, out);
}

// Round 4
// 290.984 us; speedup vs baseline: 1.5579x; 1.5579x over previous
//
#include <hip/hip_runtime.h>

// SSIM loss, streaming-row formulation.
// input [32,3,384,384] bilinear(align_corners)-> [512,512] vs target; 11x11 gaussian
// SSIM (VALID) -> mean over (96,502,502) -> loss = clip(1-mean,0,1).
//
// Per block: one plane x 32-output-row chunk, 256 threads x 2 cols = 512 cols.
// Stream region rows: stage (s=a+b, d=a-b) row in LDS (double-buffered, 1 barrier/row),
// horizontal conv of (s,d,s^2,d^2) from 12 b64 taps, vertical conv via 11-slot
// register accumulator ring (static indices). Next-row global loads issued before
// the barrier (regs survive barriers; latency hides under conv VALU).

constexpr int KS = 11;
constexpr int HI = 384, WI = 384, HO = 512, WO = 512;
constexpr int OUTD = 502;            // HO - KS + 1
constexpr int NPLANE = 96;
constexpr int CH_OUT = 32;           // output rows per chunk
constexpr int NCHUNK = 16;           // 16*32 = 512 >= 502
constexpr float C1 = 1.0e-4f;
constexpr float C2 = 9.0e-4f;

// gaussian(sigma=1.5, ks=11), normalized; matches np.float64->f32 to ~1e-7 rel
__device__ __constant__ float GW[KS] = {
    0.00102838f, 0.00759876f, 0.03600076f, 0.10936070f, 0.21300554f,
    0.26601172f, 0.21300554f, 0.10936070f, 0.03600076f, 0.00759876f, 0.00102838f};

__device__ __forceinline__ float ssim_term(float S, float D, float P, float M)
{
    float SS = S * S, DD = D * D;
    float mu12 = 0.25f * (SS - DD);          // mu1*mu2
    float musq = 0.5f  * (SS + DD);          // mu1^2 + mu2^2
    float s12  = 0.25f * (P - M) - mu12;     // sigma12
    float ssum = 0.5f  * (P + M) - musq;     // sigma1 + sigma2
    float num = fmaf(2.f, mu12, C1) * fmaf(2.f, s12, C2);
    float den = (musq + C1) * (ssum + C2);
    return __fdividef(num, den);
}

__global__ __launch_bounds__(256, 3)
void ssim_stream(const float* __restrict__ input, const float* __restrict__ target,
                 double* __restrict__ accum)
{
    __shared__ float bs[2][WO];      // s channel, double-buffered rows
    __shared__ float bd[2][WO];      // d channel
    __shared__ float wave_sums[4];

    const int tid   = threadIdx.x;
    const int chunk = blockIdx.x;
    const int plane = blockIdx.y;
    const int oyb   = chunk * CH_OUT;
    const int nout  = min(CH_OUT, OUTD - oyb);
    const int rows  = nout + KS - 1;          // region rows needed (<= 42)

    const int c0 = tid * 2, c1 = c0 + 1;

    // x-geometry (align_corners): p = c*383/511, exact-safe in f32
    int xA0, xA1, xB0, xB1; float wxA, wxB;
    {
        float pA = (float)(c0 * (WI - 1)) / (float)(WO - 1);
        xA0 = (int)pA; wxA = pA - (float)xA0; xA1 = min(xA0 + 1, WI - 1);
        float pB = (float)(c1 * (WI - 1)) / (float)(WO - 1);
        xB0 = (int)pB; wxB = pB - (float)xB0; xB1 = min(xB0 + 1, WI - 1);
    }

    const float* __restrict__ ip = input  + (size_t)plane * HI * WI;
    const float* __restrict__ tp = target + (size_t)plane * HO * WO;

    // vertical accumulator ring: slot = oy % 11, 4 channels x 2 cols
    float aS[11][2], aD[11][2], aP[11][2], aM[11][2];
    #pragma unroll
    for (int s = 0; s < 11; ++s) {
        aS[s][0] = 0.f; aS[s][1] = 0.f; aD[s][0] = 0.f; aD[s][1] = 0.f;
        aP[s][0] = 0.f; aP[s][1] = 0.f; aM[s][0] = 0.f; aM[s][1] = 0.f;
    }

    // preload registers for next region row
    float p00A, p01A, p10A, p11A, p00B, p01B, p10B, p11B, pt0, pt1, pwy;
    auto PRELOAD = [&](int r) {
        int y = oyb + r;                              // <= 511 always
        float py = (float)(y * (HI - 1)) / (float)(HO - 1);
        int y0 = (int)py; pwy = py - (float)y0;
        int y1 = min(y0 + 1, HI - 1);
        const float* r0 = ip + y0 * WI;
        const float* r1 = ip + y1 * WI;
        p00A = r0[xA0]; p01A = r0[xA1]; p10A = r1[xA0]; p11A = r1[xA1];
        p00B = r0[xB0]; p01B = r0[xB1]; p10B = r1[xB0]; p11B = r1[xB1];
        float2 tv = *(const float2*)&tp[y * WO + c0];
        pt0 = tv.x; pt1 = tv.y;
    };

    float lsum = 0.f;
    PRELOAD(0);

    for (int t = 0; t < 4; ++t) {
        #pragma unroll
        for (int i = 0; i < 11; ++i) {
            const int r = t * 11 + i;
            if (r < rows) {
                const int p = r & 1;
                // ---- stage own cols from preloaded regs
                float topA = p00A + wxA * (p01A - p00A);
                float botA = p10A + wxA * (p11A - p10A);
                float a0 = topA + pwy * (botA - topA);
                float topB = p00B + wxB * (p01B - p00B);
                float botB = p10B + wxB * (p11B - p10B);
                float a1 = topB + pwy * (botB - topB);
                float s0 = a0 + pt0, d0 = a0 - pt0;
                float s1 = a1 + pt1, d1 = a1 - pt1;
                *(float2*)&bs[p][c0] = make_float2(s0, s1);
                *(float2*)&bd[p][c0] = make_float2(d0, d1);
                // ---- issue next row's loads before the barrier (regs survive it)
                if (r + 1 < rows) PRELOAD(r + 1);
                __syncthreads();
                // ---- horizontal 11-tap conv for cols c0,c1 (12 taps union)
                float sv[12], dv[12];
                #pragma unroll
                for (int j = 0; j < 6; ++j) {
                    float2 tS = *(const float2*)&bs[p][c0 + 2 * j];
                    float2 tD = *(const float2*)&bd[p][c0 + 2 * j];
                    sv[2 * j] = tS.x; sv[2 * j + 1] = tS.y;
                    dv[2 * j] = tD.x; dv[2 * j + 1] = tD.y;
                }
                float hS0 = 0.f, hS1 = 0.f, hD0 = 0.f, hD1 = 0.f;
                float hP0 = 0.f, hP1 = 0.f, hM0 = 0.f, hM1 = 0.f;
                float svp = sv[0], dvp = dv[0];
                float sqp = svp * svp, dqp = dvp * dvp;
                #pragma unroll
                for (int j = 0; j < 11; ++j) {
                    float svn = sv[j + 1], dvn = dv[j + 1];
                    float sqn = svn * svn, dqn = dvn * dvn;
                    float w = GW[j];
                    hS0 = fmaf(w, svp, hS0); hS1 = fmaf(w, svn, hS1);
                    hD0 = fmaf(w, dvp, hD0); hD1 = fmaf(w, dvn, hD1);
                    hP0 = fmaf(w, sqp, hP0); hP1 = fmaf(w, sqn, hP1);
                    hM0 = fmaf(w, dqp, hM0); hM1 = fmaf(w, dqn, hM1);
                    svp = svn; dvp = dvn; sqp = sqn; dqp = dqn;
                }
                // ---- vertical scatter into ring (static slots)
                #pragma unroll
                for (int j = 0; j < 11; ++j) {
                    const int sl = ((i - j) % 11 + 11) % 11;
                    float w = GW[j];
                    aS[sl][0] = fmaf(w, hS0, aS[sl][0]); aS[sl][1] = fmaf(w, hS1, aS[sl][1]);
                    aD[sl][0] = fmaf(w, hD0, aD[sl][0]); aD[sl][1] = fmaf(w, hD1, aD[sl][1]);
                    aP[sl][0] = fmaf(w, hP0, aP[sl][0]); aP[sl][1] = fmaf(w, hP1, aP[sl][1]);
                    aM[sl][0] = fmaf(w, hM0, aM[sl][0]); aM[sl][1] = fmaf(w, hM1, aM[sl][1]);
                }
                // ---- output row oy = oyb + r - 10 completes; slot (i+1)%11
                const int sf = (i + 1) % 11;
                if (r >= 10) {
                    if (c0 < OUTD) {
                        lsum += ssim_term(aS[sf][0], aD[sf][0], aP[sf][0], aM[sf][0]);
                        if (c1 < OUTD)
                            lsum += ssim_term(aS[sf][1], aD[sf][1], aP[sf][1], aM[sf][1]);
                    }
                }
                // recycle slot for output oy = oyb + r + 1 (always)
                aS[sf][0] = 0.f; aS[sf][1] = 0.f; aD[sf][0] = 0.f; aD[sf][1] = 0.f;
                aP[sf][0] = 0.f; aP[sf][1] = 0.f; aM[sf][0] = 0.f; aM[sf][1] = 0.f;
            }
        }
    }

    // block reduction: wave64 shuffle + LDS across 4 waves, one f64 atomic
    #pragma unroll
    for (int off = 32; off > 0; off >>= 1) lsum += __shfl_down(lsum, off);
    int wave = tid >> 6, lane = tid & 63;
    if (lane == 0) wave_sums[wave] = lsum;
    __syncthreads();
    if (tid == 0) {
        float s = wave_sums[0] + wave_sums[1] + wave_sums[2] + wave_sums[3];
        atomicAdd(accum, (double)s);
    }
}

__global__ void ssim_finalize(const double* __restrict__ accum, float* __restrict__ out)
{
    if (threadIdx.x == 0 && blockIdx.x == 0) {
        double mean = accum[0] / ((double)NPLANE * OUTD * OUTD);
        double l = 1.0 - mean;
        if (l < 0.0) l = 0.0;
        if (l > 1.0) l = 1.0;
        out[0] = (float)l;
    }
}

extern "C" void kernel_launch(void* const* d_in, const int* in_sizes, int n_in,
                              void* d_out, int out_size, void* d_ws, size_t ws_size,
                              hipStream_t stream)
{
    const float* input  = (const float*)d_in[0];   // [32,3,384,384]
    const float* target = (const float*)d_in[1];   // [32,3,512,512]
    float* out = (float*)d_out;
    double* accum = (double*)d_ws;

    hipMemsetAsync(accum, 0, sizeof(double), stream);

    dim3 grid(NCHUNK, NPLANE);
    ssim_stream<<<grid, dim3(256), 0, stream>>>(input, target, accum);
    ssim_finalize<<<1, 64, 0, stream>>>(accum, out);
}